// Round 1
// baseline (100.149 us; speedup 1.0000x reference)
//
#include <hip/hip_runtime.h>

#define NRAYS 16384

extern "C" __global__ void nerf_render(
    const float* __restrict__ rays_o,
    const float* __restrict__ rays_d,
    const int*   __restrict__ vox_idx,
    const float* __restrict__ t_near,
    const float* __restrict__ t_far,
    const float* __restrict__ embed,
    const float* __restrict__ W1, const float* __restrict__ b1,
    const float* __restrict__ W2, const float* __restrict__ b2,
    const float* __restrict__ Wr1, const float* __restrict__ br1,
    const float* __restrict__ Wr2, const float* __restrict__ br2,
    float* __restrict__ out)
{
    const int lane = threadIdx.x & 63;
    const int wave = threadIdx.x >> 6;
    const int ray  = (blockIdx.x << 2) + wave;   // 4 waves per block, grid = 16384/4

    const int h = lane >> 2;     // hit index 0..15
    const int s = lane & 3;      // sub-sample 0..3

    const int  vi_raw = vox_idx[ray * 16 + h];
    const bool mask   = vi_raw >= 0;
    const int  vi     = mask ? vi_raw : 0;      // safe_idx, like reference

    const float tn  = t_near[ray * 16 + h];
    const float tfv = t_far [ray * 16 + h];
    const float seg = tfv - tn;
    const float t    = fmaf(seg, ((float)s + 0.5f) * 0.25f, tn);
    const float dist = seg * 0.25f;

    const float ox = rays_o[ray * 3 + 0], oy = rays_o[ray * 3 + 1], oz = rays_o[ray * 3 + 2];
    const float dx = rays_d[ray * 3 + 0], dy = rays_d[ray * 3 + 1], dz = rays_d[ray * 3 + 2];

    // ---- build MLP1 input: x = [pts(3), embed(16)] ----
    float x[19];
    x[0] = fmaf(t, dx, ox);
    x[1] = fmaf(t, dy, oy);
    x[2] = fmaf(t, dz, oz);
    const float4* er = reinterpret_cast<const float4*>(embed + (long long)vi * 16);
    float4 e0 = er[0], e1 = er[1], e2 = er[2], e3 = er[3];
    x[3]  = e0.x; x[4]  = e0.y; x[5]  = e0.z; x[6]  = e0.w;
    x[7]  = e1.x; x[8]  = e1.y; x[9]  = e1.z; x[10] = e1.w;
    x[11] = e2.x; x[12] = e2.y; x[13] = e2.z; x[14] = e2.w;
    x[15] = e3.x; x[16] = e3.y; x[17] = e3.z; x[18] = e3.w;

    // ---- MLP1: (19 -> 64 relu -> 16), hidden streamed ----
    float so[16];
    #pragma unroll
    for (int o = 0; o < 16; ++o) so[o] = b2[o];
    #pragma unroll 8
    for (int j = 0; j < 64; ++j) {
        float a = b1[j];
        #pragma unroll
        for (int i = 0; i < 19; ++i) a = fmaf(x[i], W1[i * 64 + j], a);
        a = fmaxf(a, 0.0f);
        #pragma unroll
        for (int o = 0; o < 16; ++o) so[o] = fmaf(a, W2[j * 16 + o], so[o]);
    }
    const float sdf = so[0];

    // ---- MLP2: xr = [rays_d(3), feats(15)] -> 64 relu -> 3 ----
    float xr[18];
    xr[0] = dx; xr[1] = dy; xr[2] = dz;
    #pragma unroll
    for (int i = 0; i < 15; ++i) xr[3 + i] = so[1 + i];
    float c0 = br2[0], c1 = br2[1], c2 = br2[2];
    #pragma unroll 8
    for (int j = 0; j < 64; ++j) {
        float a = br1[j];
        #pragma unroll
        for (int i = 0; i < 18; ++i) a = fmaf(xr[i], Wr1[i * 64 + j], a);
        a = fmaxf(a, 0.0f);
        c0 = fmaf(a, Wr2[j * 3 + 0], c0);
        c1 = fmaf(a, Wr2[j * 3 + 1], c1);
        c2 = fmaf(a, Wr2[j * 3 + 2], c2);
    }

    const float mf = mask ? 1.0f : 0.0f;
    const float r = mf / (1.0f + __expf(-c0));
    const float g = mf / (1.0f + __expf(-c1));
    const float b = mf / (1.0f + __expf(-c2));

    // density = (1/beta) * sigmoid(-sdf/beta), beta = 0.1
    const float density = 10.0f / (1.0f + __expf(10.0f * sdf));
    const float fe      = density * dist * mf;
    const float sdf_sc  = sdf * mf;

    // ---- inclusive scan of free energy across the wave (64 samples) ----
    float cum = fe;
    #pragma unroll
    for (int d = 1; d < 64; d <<= 1) {
        float v = __shfl_up(cum, (unsigned)d, 64);
        if (lane >= d) cum += v;
    }
    const float T     = __expf(fe - cum);       // exp(-exclusive_cumsum)
    const float alpha = 1.0f - __expf(-fe);
    const float w     = alpha * T;

    // ---- wave reductions: rgb_map(3), depth, acc ----
    float wr = w * r, wg = w * g, wb = w * b, wt = w * t, wa = w;
    #pragma unroll
    for (int d = 32; d >= 1; d >>= 1) {
        wr += __shfl_down(wr, (unsigned)d, 64);
        wg += __shfl_down(wg, (unsigned)d, 64);
        wb += __shfl_down(wb, (unsigned)d, 64);
        wt += __shfl_down(wt, (unsigned)d, 64);
        wa += __shfl_down(wa, (unsigned)d, 64);
    }

    const bool hm = (__ballot((int)mask) != 0ull);   // ray_hits recomputed

    float* out_rgb   = out;                         // [N,3]
    float* out_depth = out + NRAYS * 3;             // [N]
    float* out_disp  = out_depth + NRAYS;           // [N]
    float* out_acc   = out_disp + NRAYS;            // [N]
    float* out_w     = out_acc + NRAYS;             // [N,64]
    float* out_sdf   = out_w + NRAYS * 64;          // [N,64]

    out_w  [ray * 64 + lane] = hm ? w      : 0.0f;
    out_sdf[ray * 64 + lane] = hm ? sdf_sc : 1.0f;

    if (lane == 0) {
        if (hm) {
            out_rgb[ray * 3 + 0] = wr;
            out_rgb[ray * 3 + 1] = wg;
            out_rgb[ray * 3 + 2] = wb;
            out_depth[ray] = wt;
            out_acc[ray]   = wa;
            const float dd = wt / fmaxf(wa, 1e-10f);
            out_disp[ray]  = 1.0f / fmaxf(1e-10f, dd);
        } else {
            out_rgb[ray * 3 + 0] = 0.0f;
            out_rgb[ray * 3 + 1] = 0.0f;
            out_rgb[ray * 3 + 2] = 0.0f;
            out_depth[ray] = 0.0f;
            out_acc[ray]   = 0.0f;
            out_disp[ray]  = 1000.0f;
        }
    }
}

extern "C" void kernel_launch(void* const* d_in, const int* in_sizes, int n_in,
                              void* d_out, int out_size, void* d_ws, size_t ws_size,
                              hipStream_t stream) {
    const float* rays_o = (const float*)d_in[0];
    const float* rays_d = (const float*)d_in[1];
    const int*   vox    = (const int*)  d_in[2];
    const float* t_near = (const float*)d_in[3];
    const float* t_far  = (const float*)d_in[4];
    // d_in[5] = ray_hits (bool) — recomputed on device from vox_idx
    const float* embed  = (const float*)d_in[6];
    const float* W1  = (const float*)d_in[7];
    const float* b1  = (const float*)d_in[8];
    const float* W2  = (const float*)d_in[9];
    const float* b2  = (const float*)d_in[10];
    const float* Wr1 = (const float*)d_in[11];
    const float* br1 = (const float*)d_in[12];
    const float* Wr2 = (const float*)d_in[13];
    const float* br2 = (const float*)d_in[14];
    float* outp = (float*)d_out;

    dim3 grid(NRAYS / 4);   // 4 rays (waves) per 256-thread block
    dim3 block(256);
    nerf_render<<<grid, block, 0, stream>>>(rays_o, rays_d, vox, t_near, t_far,
                                            embed, W1, b1, W2, b2, Wr1, br1, Wr2, br2,
                                            outp);
}

// Round 2
// 90.883 us; speedup vs baseline: 1.1020x; 1.1020x over previous
//
#include <hip/hip_runtime.h>

#define NRAYS 16384

typedef _Float16 f16x8 __attribute__((ext_vector_type(8)));
typedef _Float16 f16x4 __attribute__((ext_vector_type(4)));
typedef float    f32x4 __attribute__((ext_vector_type(4)));

extern "C" __global__ __launch_bounds__(128) void nerf_render_mfma(
    const float* __restrict__ rays_o,
    const float* __restrict__ rays_d,
    const int*   __restrict__ vox_idx,
    const float* __restrict__ t_near,
    const float* __restrict__ t_far,
    const float* __restrict__ embed,
    const float* __restrict__ W1, const float* __restrict__ b1,
    const float* __restrict__ W2, const float* __restrict__ b2,
    const float* __restrict__ Wr1, const float* __restrict__ br1,
    const float* __restrict__ Wr2, const float* __restrict__ br2,
    float* __restrict__ out)
{
    // per-wave-private LDS (2 waves / block)
    __shared__ __align__(16) _Float16 x_lds[2][64][40];  // [sample][K=32 +pad8]
    __shared__ __align__(16) _Float16 h_lds[2][64][72];  // [sample][hid=64 +pad8]
    __shared__ float sdf_st[2][64];

    const int lane = threadIdx.x & 63;
    const int wv   = threadIdx.x >> 6;
    const int ray  = (blockIdx.x << 1) + wv;
    const int c = lane & 15;   // MFMA col / row-within-tile selector
    const int q = lane >> 4;   // MFMA k-group

    // ---- per-sample prologue (lane = sample index 0..63) ----
    const int hh = lane >> 2, ss = lane & 3;
    const int  vi_raw = vox_idx[ray * 16 + hh];
    const bool mask   = vi_raw >= 0;
    const int  vi     = mask ? vi_raw : 0;
    const float tn  = t_near[ray * 16 + hh];
    const float tfv = t_far [ray * 16 + hh];
    const float seg = tfv - tn;
    const float t    = fmaf(seg, ((float)ss + 0.5f) * 0.25f, tn);
    const float dist = seg * 0.25f;
    const float ox = rays_o[ray*3+0], oy = rays_o[ray*3+1], oz = rays_o[ray*3+2];
    const float dx = rays_d[ray*3+0], dy = rays_d[ray*3+1], dz = rays_d[ray*3+2];
    const float p0 = fmaf(t, dx, ox), p1 = fmaf(t, dy, oy), p2 = fmaf(t, dz, oz);
    const float4* er = reinterpret_cast<const float4*>(embed + (long long)vi * 16);
    const float4 e0 = er[0], e1 = er[1], e2 = er[2], e3 = er[3];

    // ---- weight fragments (A = W^T: row=hid=m*16+c, k=q*8+e; B: col=c, k) ----
    f16x8 w1f[4], w2f[2];
    #pragma unroll
    for (int m = 0; m < 4; ++m) {
        const int hid = m * 16 + c;
        #pragma unroll
        for (int e = 0; e < 8; ++e) {
            const int k = q * 8 + e;
            float v = 0.0f;
            if (k < 19) v = W1[k * 64 + hid];
            w1f[m][e] = (_Float16)v;
        }
        if (q == 2) w1f[m][3] = (_Float16)b1[hid];   // k==19 bias column
    }
    #pragma unroll
    for (int ks = 0; ks < 2; ++ks) {
        #pragma unroll
        for (int e = 0; e < 8; ++e) {
            const int k = ks * 32 + q * 8 + e;
            w2f[ks][e] = (_Float16)W2[k * 16 + c];
        }
    }
    const float b2c = b2[c];

    // ---- stage x row: [pts(3), emb(16), 1(bias), zeros] in f16 ----
    f16x8 r0 = {(_Float16)p0,   (_Float16)p1,   (_Float16)p2,   (_Float16)e0.x,
                (_Float16)e0.y, (_Float16)e0.z, (_Float16)e0.w, (_Float16)e1.x};
    f16x8 r1 = {(_Float16)e1.y, (_Float16)e1.z, (_Float16)e1.w, (_Float16)e2.x,
                (_Float16)e2.y, (_Float16)e2.z, (_Float16)e2.w, (_Float16)e3.x};
    f16x8 r2 = {(_Float16)e3.y, (_Float16)e3.z, (_Float16)e3.w, (_Float16)1.0f,
                (_Float16)0.0f, (_Float16)0.0f, (_Float16)0.0f, (_Float16)0.0f};
    f16x8 r3 = {(_Float16)0.0f, (_Float16)0.0f, (_Float16)0.0f, (_Float16)0.0f,
                (_Float16)0.0f, (_Float16)0.0f, (_Float16)0.0f, (_Float16)0.0f};
    *(f16x8*)&x_lds[wv][lane][0]  = r0;
    *(f16x8*)&x_lds[wv][lane][8]  = r1;
    *(f16x8*)&x_lds[wv][lane][16] = r2;
    *(f16x8*)&x_lds[wv][lane][24] = r3;

    __syncthreads();   // B0: x staged

    // ---- MLP1 layer 1: H^T = W1^T @ x^T  (M=hid 64, N=samples 64, K=32) ----
    f32x4 zero4 = {0.f, 0.f, 0.f, 0.f};
    f32x4 hacc[4][4];
    #pragma unroll
    for (int m = 0; m < 4; ++m)
        #pragma unroll
        for (int n = 0; n < 4; ++n) hacc[m][n] = zero4;

    f16x8 bx[4];
    #pragma unroll
    for (int n = 0; n < 4; ++n)
        bx[n] = *(const f16x8*)&x_lds[wv][n * 16 + c][q * 8];
    #pragma unroll
    for (int m = 0; m < 4; ++m)
        #pragma unroll
        for (int n = 0; n < 4; ++n)
            hacc[m][n] = __builtin_amdgcn_mfma_f32_16x16x32_f16(w1f[m], bx[n], hacc[m][n], 0, 0, 0);

    // relu + cvt + store H[sample][hid] (D of H^T: row=hid=m*16+q*4+j, col=sample=n*16+c)
    #pragma unroll
    for (int m = 0; m < 4; ++m)
        #pragma unroll
        for (int n = 0; n < 4; ++n) {
            f32x4 v = hacc[m][n];
            f16x4 hv;
            #pragma unroll
            for (int j = 0; j < 4; ++j) hv[j] = (_Float16)fmaxf(v[j], 0.0f);
            *(f16x4*)&h_lds[wv][n * 16 + c][m * 16 + q * 4] = hv;
        }

    __syncthreads();   // B1: H staged

    // load MLP2 weight frags here (latency overlaps layer-2 compute)
    f16x8 wr1f[4], wr2f[2];
    #pragma unroll
    for (int m = 0; m < 4; ++m) {
        const int hid = m * 16 + c;
        #pragma unroll
        for (int e = 0; e < 8; ++e) {
            const int k = q * 8 + e;
            float v = 0.0f;
            if (k < 18) v = Wr1[k * 64 + hid];
            wr1f[m][e] = (_Float16)v;
        }
        if (q == 2) wr1f[m][2] = (_Float16)br1[hid];  // k==18 bias column
    }
    #pragma unroll
    for (int ks = 0; ks < 2; ++ks) {
        #pragma unroll
        for (int e = 0; e < 8; ++e) {
            const int k = ks * 32 + q * 8 + e;
            wr2f[ks][e] = (c < 3) ? (_Float16)Wr2[k * 3 + c] : (_Float16)0.0f;
        }
    }
    const float br2c = (c < 3) ? br2[c] : 0.0f;

    // ---- MLP1 layer 2: SO = H @ W2  (M=samples, N=16, K=64) ----
    f32x4 so4[4];
    #pragma unroll
    for (int m = 0; m < 4; ++m) { so4[m][0] = b2c; so4[m][1] = b2c; so4[m][2] = b2c; so4[m][3] = b2c; }
    #pragma unroll
    for (int m = 0; m < 4; ++m)
        #pragma unroll
        for (int ks = 0; ks < 2; ++ks) {
            f16x8 af = *(const f16x8*)&h_lds[wv][m * 16 + c][ks * 32 + q * 8];
            so4[m] = __builtin_amdgcn_mfma_f32_16x16x32_f16(af, w2f[ks], so4[m], 0, 0, 0);
        }

    // ---- stage sdf + feats; rewrite own row for xr = [dir(3), feats(15), 1] ----
    x_lds[wv][lane][0]  = (_Float16)dx;
    x_lds[wv][lane][1]  = (_Float16)dy;
    x_lds[wv][lane][2]  = (_Float16)dz;
    x_lds[wv][lane][18] = (_Float16)1.0f;          // bias col (k=19.. cols stay finite, weights 0)
    if (c == 0) {
        #pragma unroll
        for (int m = 0; m < 4; ++m)
            #pragma unroll
            for (int j = 0; j < 4; ++j)
                sdf_st[wv][m * 16 + q * 4 + j] = so4[m][j];
    } else {
        #pragma unroll
        for (int m = 0; m < 4; ++m)
            #pragma unroll
            for (int j = 0; j < 4; ++j)
                x_lds[wv][m * 16 + q * 4 + j][2 + c] = (_Float16)so4[m][j];
    }

    __syncthreads();   // B2: xr staged

    // ---- MLP2 layer 1: HR^T = Wr1^T @ xr^T ----
    f32x4 hracc[4][4];
    #pragma unroll
    for (int m = 0; m < 4; ++m)
        #pragma unroll
        for (int n = 0; n < 4; ++n) hracc[m][n] = zero4;
    #pragma unroll
    for (int n = 0; n < 4; ++n)
        bx[n] = *(const f16x8*)&x_lds[wv][n * 16 + c][q * 8];
    #pragma unroll
    for (int m = 0; m < 4; ++m)
        #pragma unroll
        for (int n = 0; n < 4; ++n)
            hracc[m][n] = __builtin_amdgcn_mfma_f32_16x16x32_f16(wr1f[m], bx[n], hracc[m][n], 0, 0, 0);
    #pragma unroll
    for (int m = 0; m < 4; ++m)
        #pragma unroll
        for (int n = 0; n < 4; ++n) {
            f32x4 v = hracc[m][n];
            f16x4 hv;
            #pragma unroll
            for (int j = 0; j < 4; ++j) hv[j] = (_Float16)fmaxf(v[j], 0.0f);
            *(f16x4*)&h_lds[wv][n * 16 + c][m * 16 + q * 4] = hv;
        }

    __syncthreads();   // B3: HR staged

    // ---- MLP2 layer 2: RGB = HR @ Wr2 ----
    f32x4 rgb4[4];
    #pragma unroll
    for (int m = 0; m < 4; ++m) { rgb4[m][0] = br2c; rgb4[m][1] = br2c; rgb4[m][2] = br2c; rgb4[m][3] = br2c; }
    #pragma unroll
    for (int m = 0; m < 4; ++m)
        #pragma unroll
        for (int ks = 0; ks < 2; ++ks) {
            f16x8 af = *(const f16x8*)&h_lds[wv][m * 16 + c][ks * 32 + q * 8];
            rgb4[m] = __builtin_amdgcn_mfma_f32_16x16x32_f16(af, wr2f[ks], rgb4[m], 0, 0, 0);
        }

    float* rgb_stg = (float*)&x_lds[wv][0][0];   // x_lds dead now; reuse as [64][4] f32
    if (c < 3) {
        #pragma unroll
        for (int m = 0; m < 4; ++m)
            #pragma unroll
            for (int j = 0; j < 4; ++j)
                rgb_stg[(m * 16 + q * 4 + j) * 4 + c] = rgb4[m][j];
    }

    __syncthreads();   // B4: sdf/rgb staged

    // ---- epilogue (lane = sample) ----
    const float sdfv = sdf_st[wv][lane];
    const f32x4 rv = *(const f32x4*)&rgb_stg[lane * 4];

    const float mf = mask ? 1.0f : 0.0f;
    const float rr = mf / (1.0f + __expf(-rv[0]));
    const float gg = mf / (1.0f + __expf(-rv[1]));
    const float bb = mf / (1.0f + __expf(-rv[2]));
    const float density = 10.0f / (1.0f + __expf(10.0f * sdfv));
    const float fe      = density * dist * mf;
    const float sdf_sc  = sdfv * mf;

    float cum = fe;
    #pragma unroll
    for (int d = 1; d < 64; d <<= 1) {
        float v = __shfl_up(cum, (unsigned)d, 64);
        if (lane >= d) cum += v;
    }
    const float T     = __expf(fe - cum);
    const float alpha = 1.0f - __expf(-fe);
    const float w     = alpha * T;

    float wr = w * rr, wg = w * gg, wb = w * bb, wt = w * t, wa = w;
    #pragma unroll
    for (int d = 32; d >= 1; d >>= 1) {
        wr += __shfl_down(wr, (unsigned)d, 64);
        wg += __shfl_down(wg, (unsigned)d, 64);
        wb += __shfl_down(wb, (unsigned)d, 64);
        wt += __shfl_down(wt, (unsigned)d, 64);
        wa += __shfl_down(wa, (unsigned)d, 64);
    }

    const bool hm = (__ballot((int)mask) != 0ull);

    float* out_rgb   = out;
    float* out_depth = out + NRAYS * 3;
    float* out_disp  = out_depth + NRAYS;
    float* out_acc   = out_disp + NRAYS;
    float* out_w     = out_acc + NRAYS;
    float* out_sdf   = out_w + NRAYS * 64;

    out_w  [ray * 64 + lane] = hm ? w      : 0.0f;
    out_sdf[ray * 64 + lane] = hm ? sdf_sc : 1.0f;

    if (lane == 0) {
        if (hm) {
            out_rgb[ray * 3 + 0] = wr;
            out_rgb[ray * 3 + 1] = wg;
            out_rgb[ray * 3 + 2] = wb;
            out_depth[ray] = wt;
            out_acc[ray]   = wa;
            const float dd = wt / fmaxf(wa, 1e-10f);
            out_disp[ray]  = 1.0f / fmaxf(1e-10f, dd);
        } else {
            out_rgb[ray * 3 + 0] = 0.0f;
            out_rgb[ray * 3 + 1] = 0.0f;
            out_rgb[ray * 3 + 2] = 0.0f;
            out_depth[ray] = 0.0f;
            out_acc[ray]   = 0.0f;
            out_disp[ray]  = 1000.0f;
        }
    }
}

extern "C" void kernel_launch(void* const* d_in, const int* in_sizes, int n_in,
                              void* d_out, int out_size, void* d_ws, size_t ws_size,
                              hipStream_t stream) {
    const float* rays_o = (const float*)d_in[0];
    const float* rays_d = (const float*)d_in[1];
    const int*   vox    = (const int*)  d_in[2];
    const float* t_near = (const float*)d_in[3];
    const float* t_far  = (const float*)d_in[4];
    // d_in[5] = ray_hits (bool) — recomputed on device
    const float* embed  = (const float*)d_in[6];
    const float* W1  = (const float*)d_in[7];
    const float* b1  = (const float*)d_in[8];
    const float* W2  = (const float*)d_in[9];
    const float* b2  = (const float*)d_in[10];
    const float* Wr1 = (const float*)d_in[11];
    const float* br1 = (const float*)d_in[12];
    const float* Wr2 = (const float*)d_in[13];
    const float* br2 = (const float*)d_in[14];
    float* outp = (float*)d_out;

    dim3 grid(NRAYS / 2);   // 2 rays (waves) per 128-thread block
    dim3 block(128);
    nerf_render_mfma<<<grid, block, 0, stream>>>(rays_o, rays_d, vox, t_near, t_far,
                                                 embed, W1, b1, W2, b2, Wr1, br1, Wr2, br2,
                                                 outp);
}

// Round 3
// 58.287 us; speedup vs baseline: 1.7182x; 1.5592x over previous
//
#include <hip/hip_runtime.h>

#define NRAYS  16384
#define WPB    4        // waves per block
#define GRID   1024     // blocks -> 4096 waves -> 4 rays/wave
#define STRIDE 4096

typedef _Float16 f16x8 __attribute__((ext_vector_type(8)));
typedef _Float16 f16x4 __attribute__((ext_vector_type(4)));
typedef float    f32x4 __attribute__((ext_vector_type(4)));

// per-wave ordering: all my LDS writes visible before my later LDS reads
static __device__ __forceinline__ void wsync() {
    __builtin_amdgcn_sched_barrier(0);
    asm volatile("s_waitcnt lgkmcnt(0)" ::: "memory");
    __builtin_amdgcn_sched_barrier(0);
}

// XOR-swizzled pointer to 16B chunk `ch` (0..7) of row `row` in a [64][64] f16 tile
static __device__ __forceinline__ _Float16* rowp(_Float16* b, int row, int ch) {
    return b + (row << 6) + ((ch ^ (row & 7)) << 3);
}

extern "C" __global__ __launch_bounds__(256, 3) void nerf_render_mfma(
    const float* __restrict__ rays_o,
    const float* __restrict__ rays_d,
    const int*   __restrict__ vox_idx,
    const float* __restrict__ t_near,
    const float* __restrict__ t_far,
    const float* __restrict__ embed,
    const float* __restrict__ W1, const float* __restrict__ b1,
    const float* __restrict__ W2, const float* __restrict__ b2,
    const float* __restrict__ Wr1, const float* __restrict__ br1,
    const float* __restrict__ Wr2, const float* __restrict__ br2,
    float* __restrict__ out)
{
    __shared__ __align__(16) _Float16 buf_all[WPB][64 * 64];  // 8 KiB / wave, reused x->h->xr->hr
    __shared__ float sdf_all[WPB][64];
    __shared__ float rgb_all[WPB][64][4];

    const int lane = threadIdx.x & 63;
    const int wv   = threadIdx.x >> 6;
    _Float16* buf    = buf_all[wv];
    float*    sdf_st = sdf_all[wv];
    float   (*rgb_st)[4] = rgb_all[wv];

    const int c = lane & 15;      // MFMA col / within-tile selector
    const int q = lane >> 4;      // MFMA k-group
    const int hh = lane >> 2, ss = lane & 3;

    // ================= hoisted, loop-invariant weight fragments =================
    f16x8 w1f[4], w2f[2], wr1f[4], wr2f[2];
    #pragma unroll
    for (int m = 0; m < 4; ++m) {
        const int hid = m * 16 + c;
        #pragma unroll
        for (int e = 0; e < 8; ++e) {
            const int k = q * 8 + e;
            w1f[m][e]  = (_Float16)((k < 19) ? W1 [k * 64 + hid] : 0.0f);
            wr1f[m][e] = (_Float16)((k < 18) ? Wr1[k * 64 + hid] : 0.0f);
        }
        if (q == 2) w1f[m][3]  = (_Float16)b1 [hid];   // k==19 bias column
        if (q == 2) wr1f[m][2] = (_Float16)br1[hid];   // k==18 bias column
    }
    #pragma unroll
    for (int ks = 0; ks < 2; ++ks)
        #pragma unroll
        for (int e = 0; e < 8; ++e) {
            const int k = ks * 32 + q * 8 + e;
            w2f[ks][e]  = (_Float16)W2[k * 16 + c];
            wr2f[ks][e] = (c < 3) ? (_Float16)Wr2[k * 3 + c] : (_Float16)0.0f;
        }
    const float b2c  = b2[c];
    const float br2c = (c < 3) ? br2[c] : 0.0f;

    float* out_rgb   = out;
    float* out_depth = out + NRAYS * 3;
    float* out_disp  = out_depth + NRAYS;
    float* out_acc   = out_disp + NRAYS;
    float* out_w     = out_acc + NRAYS;
    float* out_sdf   = out_w + NRAYS * 64;

    // ================= software-pipelined ray loop =================
    int ray = blockIdx.x * WPB + wv;                 // 0..4095

    // prologue: load ray 0
    int   vi_raw = vox_idx[ray * 16 + hh];
    float tn  = t_near[ray * 16 + hh];
    float tfv = t_far [ray * 16 + hh];
    float ox = rays_o[ray*3+0], oy = rays_o[ray*3+1], oz = rays_o[ray*3+2];
    float dx = rays_d[ray*3+0], dy = rays_d[ray*3+1], dz = rays_d[ray*3+2];
    {
        const int vi = vi_raw >= 0 ? vi_raw : 0;
        const float4* er = reinterpret_cast<const float4*>(embed + (long long)vi * 16);
        // fallthrough into loop with e in regs
        float4 e0 = er[0], e1 = er[1], e2 = er[2], e3 = er[3];

        int   nvi_raw = 0;
        float ntn = 0.f, ntf = 0.f, nox = 0.f, noy = 0.f, noz = 0.f, ndx = 0.f, ndy = 0.f, ndz = 0.f;
        float4 ne0{}, ne1{}, ne2{}, ne3{};

        #pragma unroll 1
        for (int it = 0; it < 4; ++it) {
            const bool pre = (it < 3);
            const int  nray = ray + STRIDE;

            // ---- issue next ray's independent loads ASAP ----
            if (pre) {
                nvi_raw = vox_idx[nray * 16 + hh];
                ntn = t_near[nray * 16 + hh];
                ntf = t_far [nray * 16 + hh];
                nox = rays_o[nray*3+0]; noy = rays_o[nray*3+1]; noz = rays_o[nray*3+2];
                ndx = rays_d[nray*3+0]; ndy = rays_d[nray*3+1]; ndz = rays_d[nray*3+2];
            }

            // ---- current ray derived values ----
            const bool  mask = vi_raw >= 0;
            const float seg  = tfv - tn;
            const float t    = fmaf(seg, ((float)ss + 0.5f) * 0.25f, tn);
            const float dist = seg * 0.25f;
            const float p0 = fmaf(t, dx, ox), p1 = fmaf(t, dy, oy), p2 = fmaf(t, dz, oz);

            // ---- stage x = [p(3), emb(16), 1, 0...] into chunks 0..3 ----
            f16x8 r0 = {(_Float16)p0,   (_Float16)p1,   (_Float16)p2,   (_Float16)e0.x,
                        (_Float16)e0.y, (_Float16)e0.z, (_Float16)e0.w, (_Float16)e1.x};
            f16x8 r1 = {(_Float16)e1.y, (_Float16)e1.z, (_Float16)e1.w, (_Float16)e2.x,
                        (_Float16)e2.y, (_Float16)e2.z, (_Float16)e2.w, (_Float16)e3.x};
            f16x8 r2 = {(_Float16)e3.y, (_Float16)e3.z, (_Float16)e3.w, (_Float16)1.0f,
                        (_Float16)0.0f, (_Float16)0.0f, (_Float16)0.0f, (_Float16)0.0f};
            f16x8 r3 = {(_Float16)0.0f, (_Float16)0.0f, (_Float16)0.0f, (_Float16)0.0f,
                        (_Float16)0.0f, (_Float16)0.0f, (_Float16)0.0f, (_Float16)0.0f};
            *(f16x8*)rowp(buf, lane, 0) = r0;
            *(f16x8*)rowp(buf, lane, 1) = r1;
            *(f16x8*)rowp(buf, lane, 2) = r2;
            *(f16x8*)rowp(buf, lane, 3) = r3;

            wsync();   // x visible

            // ---- B-fragments of x ----
            f16x8 bx[4];
            #pragma unroll
            for (int n = 0; n < 4; ++n)
                bx[n] = *(const f16x8*)rowp(buf, n * 16 + c, q);

            // ---- issue next ray's embed gather (depends on nvi_raw) ----
            if (pre) {
                const int nvi = nvi_raw >= 0 ? nvi_raw : 0;
                const float4* ner = reinterpret_cast<const float4*>(embed + (long long)nvi * 16);
                ne0 = ner[0]; ne1 = ner[1]; ne2 = ner[2]; ne3 = ner[3];
            }

            // ---- MLP1 layer 1: H^T = W1^T @ x^T, in two M-halves (32 acc VGPRs) ----
            #pragma unroll
            for (int mh = 0; mh < 2; ++mh) {
                f32x4 acc[2][4];
                #pragma unroll
                for (int mm = 0; mm < 2; ++mm)
                    #pragma unroll
                    for (int n = 0; n < 4; ++n) { acc[mm][n][0]=0.f; acc[mm][n][1]=0.f; acc[mm][n][2]=0.f; acc[mm][n][3]=0.f; }
                #pragma unroll
                for (int mm = 0; mm < 2; ++mm)
                    #pragma unroll
                    for (int n = 0; n < 4; ++n)
                        acc[mm][n] = __builtin_amdgcn_mfma_f32_16x16x32_f16(w1f[mh*2+mm], bx[n], acc[mm][n], 0, 0, 0);
                #pragma unroll
                for (int mm = 0; mm < 2; ++mm)
                    #pragma unroll
                    for (int n = 0; n < 4; ++n) {
                        f16x4 hv;
                        #pragma unroll
                        for (int j = 0; j < 4; ++j) hv[j] = (_Float16)fmaxf(acc[mm][n][j], 0.0f);
                        const int m   = mh * 2 + mm;
                        const int row = n * 16 + c;
                        const int ch  = m * 2 + (q >> 1);          // col m*16+q*4 -> chunk
                        *(f16x4*)(rowp(buf, row, ch) + ((q & 1) << 2)) = hv;
                    }
            }

            wsync();   // H visible

            // ---- MLP1 layer 2: SO = H @ W2 ----
            f32x4 so4[4];
            #pragma unroll
            for (int m = 0; m < 4; ++m) { so4[m][0]=b2c; so4[m][1]=b2c; so4[m][2]=b2c; so4[m][3]=b2c; }
            #pragma unroll
            for (int m = 0; m < 4; ++m)
                #pragma unroll
                for (int ks = 0; ks < 2; ++ks) {
                    f16x8 af = *(const f16x8*)rowp(buf, m * 16 + c, ks * 4 + q);
                    so4[m] = __builtin_amdgcn_mfma_f32_16x16x32_f16(af, w2f[ks], so4[m], 0, 0, 0);
                }

            // ---- stage xr = [dir(3), feats(15), 1] (chunks 0..2); sdf -> sdf_st ----
            {
                _Float16* my0 = rowp(buf, lane, 0);
                my0[0] = (_Float16)dx; my0[1] = (_Float16)dy; my0[2] = (_Float16)dz;
                rowp(buf, lane, 2)[2] = (_Float16)1.0f;        // col 18 bias
            }
            if (c == 0) {
                #pragma unroll
                for (int m = 0; m < 4; ++m)
                    #pragma unroll
                    for (int j = 0; j < 4; ++j)
                        sdf_st[m * 16 + q * 4 + j] = so4[m][j];
            } else {
                const int col = 2 + c;                          // 3..17
                #pragma unroll
                for (int m = 0; m < 4; ++m)
                    #pragma unroll
                    for (int j = 0; j < 4; ++j) {
                        const int row = m * 16 + q * 4 + j;
                        *(rowp(buf, row, col >> 3) + (col & 7)) = (_Float16)so4[m][j];
                    }
            }

            wsync();   // xr + sdf visible

            // ---- MLP2 layer 1: HR^T = Wr1^T @ xr^T ----
            #pragma unroll
            for (int n = 0; n < 4; ++n)
                bx[n] = *(const f16x8*)rowp(buf, n * 16 + c, q);
            #pragma unroll
            for (int mh = 0; mh < 2; ++mh) {
                f32x4 acc[2][4];
                #pragma unroll
                for (int mm = 0; mm < 2; ++mm)
                    #pragma unroll
                    for (int n = 0; n < 4; ++n) { acc[mm][n][0]=0.f; acc[mm][n][1]=0.f; acc[mm][n][2]=0.f; acc[mm][n][3]=0.f; }
                #pragma unroll
                for (int mm = 0; mm < 2; ++mm)
                    #pragma unroll
                    for (int n = 0; n < 4; ++n)
                        acc[mm][n] = __builtin_amdgcn_mfma_f32_16x16x32_f16(wr1f[mh*2+mm], bx[n], acc[mm][n], 0, 0, 0);
                #pragma unroll
                for (int mm = 0; mm < 2; ++mm)
                    #pragma unroll
                    for (int n = 0; n < 4; ++n) {
                        f16x4 hv;
                        #pragma unroll
                        for (int j = 0; j < 4; ++j) hv[j] = (_Float16)fmaxf(acc[mm][n][j], 0.0f);
                        const int m   = mh * 2 + mm;
                        const int row = n * 16 + c;
                        const int ch  = m * 2 + (q >> 1);
                        *(f16x4*)(rowp(buf, row, ch) + ((q & 1) << 2)) = hv;
                    }
            }

            wsync();   // HR visible

            // ---- MLP2 layer 2: RGB = HR @ Wr2 ----
            f32x4 rgb4[4];
            #pragma unroll
            for (int m = 0; m < 4; ++m) { rgb4[m][0]=br2c; rgb4[m][1]=br2c; rgb4[m][2]=br2c; rgb4[m][3]=br2c; }
            #pragma unroll
            for (int m = 0; m < 4; ++m)
                #pragma unroll
                for (int ks = 0; ks < 2; ++ks) {
                    f16x8 af = *(const f16x8*)rowp(buf, m * 16 + c, ks * 4 + q);
                    rgb4[m] = __builtin_amdgcn_mfma_f32_16x16x32_f16(af, wr2f[ks], rgb4[m], 0, 0, 0);
                }
            if (c < 3) {
                #pragma unroll
                for (int m = 0; m < 4; ++m)
                    #pragma unroll
                    for (int j = 0; j < 4; ++j)
                        rgb_st[m * 16 + q * 4 + j][c] = rgb4[m][j];
            }

            wsync();   // rgb visible

            // ---- epilogue (lane = sample) ----
            const float sdfv = sdf_st[lane];
            const float rv0 = rgb_st[lane][0], rv1 = rgb_st[lane][1], rv2 = rgb_st[lane][2];

            const float mf = mask ? 1.0f : 0.0f;
            const float rr = mf / (1.0f + __expf(-rv0));
            const float gg = mf / (1.0f + __expf(-rv1));
            const float bb = mf / (1.0f + __expf(-rv2));
            const float density = 10.0f / (1.0f + __expf(10.0f * sdfv));
            const float fe      = density * dist * mf;
            const float sdf_sc  = sdfv * mf;

            float cum = fe;
            #pragma unroll
            for (int d = 1; d < 64; d <<= 1) {
                float v = __shfl_up(cum, (unsigned)d, 64);
                if (lane >= d) cum += v;
            }
            const float T     = __expf(fe - cum);
            const float alpha = 1.0f - __expf(-fe);
            const float w     = alpha * T;

            float wr = w * rr, wg = w * gg, wb = w * bb, wt = w * t, wa = w;
            #pragma unroll
            for (int d = 32; d >= 1; d >>= 1) {
                wr += __shfl_down(wr, (unsigned)d, 64);
                wg += __shfl_down(wg, (unsigned)d, 64);
                wb += __shfl_down(wb, (unsigned)d, 64);
                wt += __shfl_down(wt, (unsigned)d, 64);
                wa += __shfl_down(wa, (unsigned)d, 64);
            }

            const bool hm = (__ballot((int)mask) != 0ull);

            out_w  [ray * 64 + lane] = hm ? w      : 0.0f;
            out_sdf[ray * 64 + lane] = hm ? sdf_sc : 1.0f;
            if (lane == 0) {
                if (hm) {
                    out_rgb[ray * 3 + 0] = wr;
                    out_rgb[ray * 3 + 1] = wg;
                    out_rgb[ray * 3 + 2] = wb;
                    out_depth[ray] = wt;
                    out_acc[ray]   = wa;
                    const float dd = wt / fmaxf(wa, 1e-10f);
                    out_disp[ray]  = 1.0f / fmaxf(1e-10f, dd);
                } else {
                    out_rgb[ray * 3 + 0] = 0.0f;
                    out_rgb[ray * 3 + 1] = 0.0f;
                    out_rgb[ray * 3 + 2] = 0.0f;
                    out_depth[ray] = 0.0f;
                    out_acc[ray]   = 0.0f;
                    out_disp[ray]  = 1000.0f;
                }
            }

            // ---- rotate pipeline regs ----
            ray = nray;
            vi_raw = nvi_raw; tn = ntn; tfv = ntf;
            ox = nox; oy = noy; oz = noz; dx = ndx; dy = ndy; dz = ndz;
            e0 = ne0; e1 = ne1; e2 = ne2; e3 = ne3;
        }
    }
}

extern "C" void kernel_launch(void* const* d_in, const int* in_sizes, int n_in,
                              void* d_out, int out_size, void* d_ws, size_t ws_size,
                              hipStream_t stream) {
    const float* rays_o = (const float*)d_in[0];
    const float* rays_d = (const float*)d_in[1];
    const int*   vox    = (const int*)  d_in[2];
    const float* t_near = (const float*)d_in[3];
    const float* t_far  = (const float*)d_in[4];
    // d_in[5] = ray_hits (bool) — recomputed on device
    const float* embed  = (const float*)d_in[6];
    const float* W1  = (const float*)d_in[7];
    const float* b1  = (const float*)d_in[8];
    const float* W2  = (const float*)d_in[9];
    const float* b2  = (const float*)d_in[10];
    const float* Wr1 = (const float*)d_in[11];
    const float* br1 = (const float*)d_in[12];
    const float* Wr2 = (const float*)d_in[13];
    const float* br2 = (const float*)d_in[14];
    float* outp = (float*)d_out;

    nerf_render_mfma<<<dim3(GRID), dim3(256), 0, stream>>>(rays_o, rays_d, vox, t_near, t_far,
                                                           embed, W1, b1, W2, b2, Wr1, br1, Wr2, br2,
                                                           outp);
}

// Round 4
// 39.154 us; speedup vs baseline: 2.5578x; 1.4886x over previous
//
#include <hip/hip_runtime.h>

#define NRAYS  16384
#define WPB    4
#define GRID   1024
#define STRIDE 4096

typedef _Float16 f16x2 __attribute__((ext_vector_type(2)));
typedef _Float16 f16x4 __attribute__((ext_vector_type(4)));
typedef _Float16 f16x8 __attribute__((ext_vector_type(8)));
typedef float    f32x4 __attribute__((ext_vector_type(4)));

static __device__ __forceinline__ f16x2 pk(float a, float b) {
    return __builtin_bit_cast(f16x2, __builtin_amdgcn_cvt_pkrtz(a, b));
}
static __device__ __forceinline__ f16x4 cat2(f16x2 lo, f16x2 hi) {
    return __builtin_shufflevector(lo, hi, 0, 1, 2, 3);
}
static __device__ __forceinline__ f16x4 pack4relu(f32x4 v) {
    return cat2(pk(fmaxf(v[0], 0.f), fmaxf(v[1], 0.f)),
                pk(fmaxf(v[2], 0.f), fmaxf(v[3], 0.f)));
}
template <int CTRL, int RMASK>
static __device__ __forceinline__ float dppadd(float x) {
    int t = __builtin_amdgcn_update_dpp(0, __builtin_bit_cast(int, x), CTRL, RMASK, 0xf, true);
    return x + __builtin_bit_cast(float, t);
}
// inclusive 64-lane sum scan, pure VALU (no DS pipe)
static __device__ __forceinline__ float wavescan(float x) {
    x = dppadd<0x111, 0xf>(x);   // row_shr:1
    x = dppadd<0x112, 0xf>(x);   // row_shr:2
    x = dppadd<0x114, 0xf>(x);   // row_shr:4
    x = dppadd<0x118, 0xf>(x);   // row_shr:8
    x = dppadd<0x142, 0xa>(x);   // row_bcast:15 -> rows 1,3
    x = dppadd<0x143, 0xc>(x);   // row_bcast:31 -> rows 2,3
    return x;
}
static __device__ __forceinline__ float lane63(float x) {
    return __builtin_bit_cast(float, __builtin_amdgcn_readlane(__builtin_bit_cast(int, x), 63));
}
// XOR-swizzled pointer to 16B chunk `ch` of row `row` in a [64][64]-f16 tile
static __device__ __forceinline__ _Float16* rowp(_Float16* b, int row, int ch) {
    return b + (row << 6) + ((ch ^ (row & 7)) << 3);
}

#define MFMA32(a, b, c) __builtin_amdgcn_mfma_f32_16x16x32_f16(a, b, c, 0, 0, 0)
#define MFMA16(a, b, c) __builtin_amdgcn_mfma_f32_16x16x16f16(a, b, c, 0, 0, 0)

extern "C" __global__ __launch_bounds__(256, 3) void nerf_render_mfma(
    const float* __restrict__ rays_o,
    const float* __restrict__ rays_d,
    const int*   __restrict__ vox_idx,
    const float* __restrict__ t_near,
    const float* __restrict__ t_far,
    const float* __restrict__ embed,
    const float* __restrict__ W1, const float* __restrict__ b1,
    const float* __restrict__ W2, const float* __restrict__ b2,
    const float* __restrict__ Wr1, const float* __restrict__ br1,
    const float* __restrict__ Wr2, const float* __restrict__ br2,
    float* __restrict__ out)
{
    __shared__ __align__(16) _Float16 buf_all[WPB][64 * 64];   // 8KB/wave: x-stage + rgb handoff

    const int lane = threadIdx.x & 63;
    const int wv   = threadIdx.x >> 6;
    _Float16* buf = buf_all[wv];
    f32x4* rgbbuf = reinterpret_cast<f32x4*>(buf);             // rows 0..7 reused post-L1

    const int c  = lane & 15;
    const int q  = lane >> 4;
    const bool q0 = (q == 0);
    const int hh = lane >> 2, ss = lane & 3;
    const int bpaddr = ((lane + 48) & 63) << 2;                // lane-16 (mod 64), byte addr

    // ===== hoisted weight fragments =====
    // L1 (16x16x32): A = W1^T, row=hid=m*16+c, k=q*8+e (k==19 -> bias col)
    f16x8 w1f[4];
    #pragma unroll
    for (int m = 0; m < 4; ++m) {
        const int hid = m * 16 + c;
        #pragma unroll
        for (int e = 0; e < 8; ++e) {
            const int k = q * 8 + e;
            w1f[m][e] = (_Float16)((k < 19) ? W1[k * 64 + hid] : (k == 19 ? b1[hid] : 0.f));
        }
    }
    // L2 (16x16x16): A = W2^T, row=o=c, k-step mh: k=16*mh+q*4+e
    f16x4 w2a[4];
    #pragma unroll
    for (int mh = 0; mh < 4; ++mh)
        #pragma unroll
        for (int e = 0; e < 4; ++e)
            w2a[mh][e] = (_Float16)W2[(mh * 16 + q * 4 + e) * 16 + c];
    // L3 (16x16x16): A = Wr1^T, row=hid=mh*16+c, 2 k-steps, k=ks*16+q*4+e (k==18 -> bias)
    f16x4 wr1a[4][2];
    #pragma unroll
    for (int mh = 0; mh < 4; ++mh) {
        const int hid = mh * 16 + c;
        #pragma unroll
        for (int ks = 0; ks < 2; ++ks)
            #pragma unroll
            for (int e = 0; e < 4; ++e) {
                const int k = ks * 16 + q * 4 + e;
                wr1a[mh][ks][e] = (_Float16)((k < 18) ? Wr1[k * 64 + hid]
                                                      : (k == 18 ? br1[hid] : 0.f));
            }
    }
    // L4 (16x16x16): A = Wr2^T, row=o=c (<3), k=16*mh+q*4+e
    f16x4 wr2a[4];
    #pragma unroll
    for (int mh = 0; mh < 4; ++mh)
        #pragma unroll
        for (int e = 0; e < 4; ++e)
            wr2a[mh][e] = (c < 3) ? (_Float16)Wr2[(mh * 16 + q * 4 + e) * 3 + c] : (_Float16)0.f;

    float b2v[4], br2v[4];
    #pragma unroll
    for (int j = 0; j < 4; ++j) {
        b2v[j]  = b2[q * 4 + j];
        br2v[j] = (q * 4 + j) < 3 ? br2[q * 4 + j] : 0.f;
    }

    float* out_rgb   = out;
    float* out_depth = out + NRAYS * 3;
    float* out_disp  = out_depth + NRAYS;
    float* out_acc   = out_disp + NRAYS;
    float* out_w     = out_acc + NRAYS;
    float* out_sdf   = out_w + NRAYS * 64;

    int ray = blockIdx.x * WPB + wv;

    // prologue: load ray 0
    int   vi_raw = vox_idx[ray * 16 + hh];
    float tn  = t_near[ray * 16 + hh];
    float tfv = t_far [ray * 16 + hh];
    float ox = rays_o[ray*3+0], oy = rays_o[ray*3+1], oz = rays_o[ray*3+2];
    float dx = rays_d[ray*3+0], dy = rays_d[ray*3+1], dz = rays_d[ray*3+2];
    {
        const int vi0 = vi_raw >= 0 ? vi_raw : 0;
        const float4* er = reinterpret_cast<const float4*>(embed + (long long)vi0 * 16);
        float4 e0 = er[0], e1 = er[1], e2 = er[2], e3 = er[3];

        int   nvi_raw = 0;
        float ntn = 0.f, ntf = 0.f, nox = 0.f, noy = 0.f, noz = 0.f, ndx = 0.f, ndy = 0.f, ndz = 0.f;
        float4 ne0{}, ne1{}, ne2{}, ne3{};

        #pragma unroll 1
        for (int it = 0; it < 4; ++it) {
            const bool pre = (it < 3);
            const int  nray = ray + STRIDE;

            if (pre) {
                nvi_raw = vox_idx[nray * 16 + hh];
                ntn = t_near[nray * 16 + hh];
                ntf = t_far [nray * 16 + hh];
                nox = rays_o[nray*3+0]; noy = rays_o[nray*3+1]; noz = rays_o[nray*3+2];
                ndx = rays_d[nray*3+0]; ndy = rays_d[nray*3+1]; ndz = rays_d[nray*3+2];
            }

            const bool  mask = vi_raw >= 0;
            const float seg  = tfv - tn;
            const float t    = fmaf(seg, ((float)ss + 0.5f) * 0.25f, tn);
            const float dist = seg * 0.25f;
            const float p0 = fmaf(t, dx, ox), p1 = fmaf(t, dy, oy), p2 = fmaf(t, dz, oz);

            // ---- stage x = [p(3), emb(16), 1, 0...] (chunks 0..3) ----
            f16x8 r0 = {(_Float16)p0,   (_Float16)p1,   (_Float16)p2,   (_Float16)e0.x,
                        (_Float16)e0.y, (_Float16)e0.z, (_Float16)e0.w, (_Float16)e1.x};
            f16x8 r1 = {(_Float16)e1.y, (_Float16)e1.z, (_Float16)e1.w, (_Float16)e2.x,
                        (_Float16)e2.y, (_Float16)e2.z, (_Float16)e2.w, (_Float16)e3.x};
            f16x8 r2 = {(_Float16)e3.y, (_Float16)e3.z, (_Float16)e3.w, (_Float16)1.0f,
                        (_Float16)0.0f, (_Float16)0.0f, (_Float16)0.0f, (_Float16)0.0f};
            f16x8 r3 = {};
            *(f16x8*)rowp(buf, lane, 0) = r0;
            *(f16x8*)rowp(buf, lane, 1) = r1;
            *(f16x8*)rowp(buf, lane, 2) = r2;
            *(f16x8*)rowp(buf, lane, 3) = r3;

            // ---- B-fragments of x (compiler inserts lgkmcnt) ----
            f16x8 bx[4];
            #pragma unroll
            for (int n = 0; n < 4; ++n)
                bx[n] = *(const f16x8*)rowp(buf, n * 16 + c, q);

            if (pre) {
                const int nvi = nvi_raw >= 0 ? nvi_raw : 0;
                const float4* ner = reinterpret_cast<const float4*>(embed + (long long)nvi * 16);
                ne0 = ner[0]; ne1 = ner[1]; ne2 = ner[2]; ne3 = ner[3];
            }

            // ---- L1 (x32) fused with L2 (x16, B = L1 acc regs directly) ----
            f32x4 acc2[4];
            #pragma unroll
            for (int n = 0; n < 4; ++n) acc2[n] = (f32x4){b2v[0], b2v[1], b2v[2], b2v[3]};
            #pragma unroll
            for (int m = 0; m < 4; ++m) {
                f32x4 a1[4] = {};
                #pragma unroll
                for (int n = 0; n < 4; ++n) a1[n] = MFMA32(w1f[m], bx[n], a1[n]);
                f16x4 hb[4];
                #pragma unroll
                for (int n = 0; n < 4; ++n) hb[n] = pack4relu(a1[n]);
                #pragma unroll
                for (int n = 0; n < 4; ++n) acc2[n] = MFMA16(w2a[m], hb[n], acc2[n]);
            }
            // acc2 = SO^T tile: lane(q,c) holds SO[16n+c][q*4+j]

            // ---- build L3 B-fragments: xr^T, k=ks*16+q*4+e over [dir(3),feats(15),1] ----
            float sdfv[4]; f16x2 d0[4], d1[4]; int bd[4];
            #pragma unroll
            for (int n = 0; n < 4; ++n) {
                sdfv[n] = acc2[n][0];
                d0[n] = pk(acc2[n][0], acc2[n][1]);
                d1[n] = pk(acc2[n][2], acc2[n][3]);
            }
            #pragma unroll
            for (int n = 0; n < 4; ++n)
                bd[n] = __builtin_amdgcn_ds_bpermute(bpaddr, __builtin_bit_cast(int, d1[n]));

            const f16x2 dir01 = pk(dx, dy);
            const _Float16 dzh = (_Float16)dz;
            const f16x2 zero2 = {};
            const f16x2 onezero = {(_Float16)1.0f, (_Float16)0.0f};
            f16x4 bfr0[4], bfr1[4];
            #pragma unroll
            for (int n = 0; n < 4; ++n) {
                f16x2 bdn = __builtin_bit_cast(f16x2, bd[n]);
                f16x2 lo0 = q0 ? dir01 : bdn;                       // k=q*4+0,1
                f16x2 hi0 = q0 ? (f16x2){dzh, d0[n][1]} : d0[n];    // k=q*4+2,3
                bfr0[n] = cat2(lo0, hi0);
                f16x2 lo1 = q0 ? bdn : zero2;                       // k=16,17 (o=14,15)
                f16x2 hi1 = q0 ? onezero : zero2;                   // k=18 bias, 19 zero
                bfr1[n] = cat2(lo1, hi1);
            }

            // ---- L3 (x16, 2 k-steps) fused with L4 (x16, B = L3 acc regs) ----
            f32x4 acc4[4];
            #pragma unroll
            for (int n = 0; n < 4; ++n) acc4[n] = (f32x4){br2v[0], br2v[1], br2v[2], br2v[3]};
            #pragma unroll
            for (int mh = 0; mh < 4; ++mh) {
                f32x4 a3[4] = {};
                #pragma unroll
                for (int n = 0; n < 4; ++n) a3[n] = MFMA16(wr1a[mh][0], bfr0[n], a3[n]);
                #pragma unroll
                for (int n = 0; n < 4; ++n) a3[n] = MFMA16(wr1a[mh][1], bfr1[n], a3[n]);
                f16x4 hr[4];
                #pragma unroll
                for (int n = 0; n < 4; ++n) hr[n] = pack4relu(a3[n]);
                #pragma unroll
                for (int n = 0; n < 4; ++n) acc4[n] = MFMA16(wr2a[mh], hr[n], acc4[n]);
            }
            // acc4 = RGB^T: q=0 lanes hold outs 0..3 for samples 16n+c

            // ---- handoff {r,g,b,sdf} via 1KB of buf ----
            if (q0) {
                #pragma unroll
                for (int n = 0; n < 4; ++n) {
                    f32x4 o4 = {acc4[n][0], acc4[n][1], acc4[n][2], sdfv[n]};
                    rgbbuf[n * 16 + c] = o4;
                }
            }
            const f32x4 mine = rgbbuf[lane];

            // ---- epilogue (lane = sample), scan/reduce on DPP (VALU) ----
            const float sdfs = mine[3];
            const float mf = mask ? 1.0f : 0.0f;
            const float rr = mf / (1.0f + __expf(-mine[0]));
            const float gg = mf / (1.0f + __expf(-mine[1]));
            const float bb = mf / (1.0f + __expf(-mine[2]));
            const float density = 10.0f / (1.0f + __expf(10.0f * sdfs));
            const float fe      = density * dist * mf;
            const float sdf_sc  = sdfs * mf;

            const float cum   = wavescan(fe);
            const float T     = __expf(fe - cum);
            const float alpha = 1.0f - __expf(-fe);
            const float w     = alpha * T;

            const float swr = lane63(wavescan(w * rr));
            const float swg = lane63(wavescan(w * gg));
            const float swb = lane63(wavescan(w * bb));
            const float swt = lane63(wavescan(w * t));
            const float swa = lane63(wavescan(w));

            const bool hm = (__ballot((int)mask) != 0ull);

            out_w  [ray * 64 + lane] = hm ? w      : 0.0f;
            out_sdf[ray * 64 + lane] = hm ? sdf_sc : 1.0f;
            if (lane == 0) {
                if (hm) {
                    out_rgb[ray * 3 + 0] = swr;
                    out_rgb[ray * 3 + 1] = swg;
                    out_rgb[ray * 3 + 2] = swb;
                    out_depth[ray] = swt;
                    out_acc[ray]   = swa;
                    const float dd = swt / fmaxf(swa, 1e-10f);
                    out_disp[ray]  = 1.0f / fmaxf(1e-10f, dd);
                } else {
                    out_rgb[ray * 3 + 0] = 0.0f;
                    out_rgb[ray * 3 + 1] = 0.0f;
                    out_rgb[ray * 3 + 2] = 0.0f;
                    out_depth[ray] = 0.0f;
                    out_acc[ray]   = 0.0f;
                    out_disp[ray]  = 1000.0f;
                }
            }

            ray = nray;
            vi_raw = nvi_raw; tn = ntn; tfv = ntf;
            ox = nox; oy = noy; oz = noz; dx = ndx; dy = ndy; dz = ndz;
            e0 = ne0; e1 = ne1; e2 = ne2; e3 = ne3;
        }
    }
}

extern "C" void kernel_launch(void* const* d_in, const int* in_sizes, int n_in,
                              void* d_out, int out_size, void* d_ws, size_t ws_size,
                              hipStream_t stream) {
    const float* rays_o = (const float*)d_in[0];
    const float* rays_d = (const float*)d_in[1];
    const int*   vox    = (const int*)  d_in[2];
    const float* t_near = (const float*)d_in[3];
    const float* t_far  = (const float*)d_in[4];
    // d_in[5] = ray_hits (bool) — recomputed on device
    const float* embed  = (const float*)d_in[6];
    const float* W1  = (const float*)d_in[7];
    const float* b1  = (const float*)d_in[8];
    const float* W2  = (const float*)d_in[9];
    const float* b2  = (const float*)d_in[10];
    const float* Wr1 = (const float*)d_in[11];
    const float* br1 = (const float*)d_in[12];
    const float* Wr2 = (const float*)d_in[13];
    const float* br2 = (const float*)d_in[14];
    float* outp = (float*)d_out;

    nerf_render_mfma<<<dim3(GRID), dim3(256), 0, stream>>>(rays_o, rays_d, vox, t_near, t_far,
                                                           embed, W1, b1, W2, b2, Wr1, br1, Wr2, br2,
                                                           outp);
}